// Round 1
// baseline (1291.362 us; speedup 1.0000x reference)
//
#include <hip/hip_runtime.h>

#define NCH 128  // feature channels for all aggregation stages

// ---------------- CSR build ----------------

__global__ void gin_deg_kernel(const int* __restrict__ dst, int* __restrict__ off, int E) {
    int e = blockIdx.x * 256 + threadIdx.x;
    if (e < E) atomicAdd(&off[dst[e] + 1], 1);
}

// single-block inclusive scan over off[0..n-1] (n = N+1), in place
__global__ void gin_scan_kernel(int* __restrict__ off, int n) {
    __shared__ int part[1024];
    int t = threadIdx.x;
    int chunk = (n + 1023) / 1024;
    int lo = t * chunk;
    int hi = min(lo + chunk, n);
    int s = 0;
    for (int i = lo; i < hi; ++i) s += off[i];
    part[t] = s;
    __syncthreads();
    for (int o = 1; o < 1024; o <<= 1) {
        int v = (t >= o) ? part[t - o] : 0;
        __syncthreads();
        part[t] += v;
        __syncthreads();
    }
    int run = (t == 0) ? 0 : part[t - 1];
    for (int i = lo; i < hi; ++i) { run += off[i]; off[i] = run; }
}

__global__ void gin_copy_kernel(const int* __restrict__ off, int* __restrict__ cursor, int n) {
    int i = blockIdx.x * 256 + threadIdx.x;
    if (i < n) cursor[i] = off[i];
}

__global__ void gin_fill_kernel(const int* __restrict__ src, const int* __restrict__ dst,
                                int* __restrict__ cursor, int* __restrict__ csr, int E) {
    int e = blockIdx.x * 256 + threadIdx.x;
    if (e < E) {
        int d = dst[e];
        int p = atomicAdd(&cursor[d], 1);
        csr[p] = src[e];
    }
}

// ---------------- aggregation: z = (1+eps)*h + mean_neigh ----------------
// 2 nodes per 256-thread block; 128 threads = 128 channels per node.
__global__ void gin_agg_kernel(const float* __restrict__ h, const int* __restrict__ off,
                               const int* __restrict__ csr, const float* __restrict__ eps,
                               int layer, float* __restrict__ z, int n) {
    int node = blockIdx.x * 2 + (threadIdx.x >> 7);
    int c = threadIdx.x & 127;
    if (node >= n) return;
    int lo = off[node], hi = off[node + 1];
    float sum = 0.f;
    for (int e = lo; e < hi; ++e) {
        int s = csr[e];
        sum += h[(size_t)s * NCH + c];
    }
    float deg = (float)(hi - lo);
    float mean = sum / fmaxf(deg, 1.0f);
    float e1 = 1.0f + eps[layer];
    z[(size_t)node * NCH + c] = e1 * h[(size_t)node * NCH + c] + mean;
}

// ---------------- fused 2-layer MLP: out = leaky(leaky(Z@W1+b1)@W2+b2) ----------------
// 64 rows per block, 256 threads. thread (tr,tc) computes rows tr*4..tr*4+3,
// cols tc*CPT..tc*CPT+CPT-1. Z tile and T (intermediate) share one LDS buffer.
template <int N1, int N2>
__global__ __launch_bounds__(256)
void gin_mlp_kernel(const float* __restrict__ Z,
                    const float* __restrict__ W1, const float* __restrict__ B1,
                    const float* __restrict__ W2, const float* __restrict__ B2,
                    float* __restrict__ Out, int nrows) {
    constexpr int K1 = 128;
    constexpr int CPT1 = N1 / 16;
    constexpr int CPT2 = N2 / 16;
    constexpr int ZSTRIDE = 132;  // pad 128 -> 132 (keeps 16B align, 2-way-max conflicts)

    __shared__ float Zs[64 * ZSTRIDE];
    __shared__ float Ws[32 * 128];

    int tid = threadIdx.x;
    int tr = tid >> 4;   // 0..15
    int tc = tid & 15;   // 0..15
    int m0 = blockIdx.x * 64;

    // load Z tile (64 x 128) via float4, zero-pad OOB rows
    #pragma unroll
    for (int it = 0; it < 8; ++it) {
        int idx4 = tid + it * 256;
        int m = idx4 >> 5;
        int k4 = idx4 & 31;
        float4 v = make_float4(0.f, 0.f, 0.f, 0.f);
        if (m0 + m < nrows) v = ((const float4*)(Z + (size_t)(m0 + m) * K1))[k4];
        *(float4*)&Zs[m * ZSTRIDE + k4 * 4] = v;
    }

    // ---- phase 1: T = leaky(Z @ W1 + b1) ----
    float acc[4][CPT1];
    #pragma unroll
    for (int i = 0; i < 4; ++i)
        #pragma unroll
        for (int j = 0; j < CPT1; ++j) acc[i][j] = 0.f;

    for (int kc = 0; kc < K1 / 32; ++kc) {
        __syncthreads();
        #pragma unroll
        for (int it = 0; it < (32 * N1) / 1024; ++it) {
            int idx4 = tid + it * 256;
            int kk = idx4 / (N1 / 4);
            int j4 = idx4 % (N1 / 4);
            *(float4*)&Ws[kk * N1 + j4 * 4] =
                ((const float4*)(W1 + (size_t)(kc * 32 + kk) * N1))[j4];
        }
        __syncthreads();
        #pragma unroll
        for (int kk = 0; kk < 32; ++kk) {
            int k = kc * 32 + kk;
            float a[4];
            #pragma unroll
            for (int i = 0; i < 4; ++i) a[i] = Zs[(tr * 4 + i) * ZSTRIDE + k];
            float b[CPT1];
            #pragma unroll
            for (int j = 0; j < CPT1; ++j) b[j] = Ws[kk * N1 + tc * CPT1 + j];
            #pragma unroll
            for (int i = 0; i < 4; ++i)
                #pragma unroll
                for (int j = 0; j < CPT1; ++j) acc[i][j] = fmaf(a[i], b[j], acc[i][j]);
        }
    }
    __syncthreads();  // all phase-1 reads of Zs/Ws done

    // bias + leaky, write T into Zs (same layout)
    #pragma unroll
    for (int i = 0; i < 4; ++i) {
        #pragma unroll
        for (int j = 0; j < CPT1; ++j) {
            float v = acc[i][j] + B1[tc * CPT1 + j];
            v = v > 0.f ? v : 0.01f * v;
            Zs[(tr * 4 + i) * ZSTRIDE + tc * CPT1 + j] = v;
        }
    }

    // ---- phase 2: out = leaky(T @ W2 + b2) ----
    float acc2[4][CPT2];
    #pragma unroll
    for (int i = 0; i < 4; ++i)
        #pragma unroll
        for (int j = 0; j < CPT2; ++j) acc2[i][j] = 0.f;

    for (int kc = 0; kc < N1 / 32; ++kc) {
        __syncthreads();  // (first iter: also publishes T writes)
        #pragma unroll
        for (int it = 0; it < (32 * N2) / 1024; ++it) {
            int idx4 = tid + it * 256;
            int kk = idx4 / (N2 / 4);
            int j4 = idx4 % (N2 / 4);
            *(float4*)&Ws[kk * N2 + j4 * 4] =
                ((const float4*)(W2 + (size_t)(kc * 32 + kk) * N2))[j4];
        }
        __syncthreads();
        #pragma unroll
        for (int kk = 0; kk < 32; ++kk) {
            int k = kc * 32 + kk;
            float a[4];
            #pragma unroll
            for (int i = 0; i < 4; ++i) a[i] = Zs[(tr * 4 + i) * ZSTRIDE + k];
            float b[CPT2];
            #pragma unroll
            for (int j = 0; j < CPT2; ++j) b[j] = Ws[kk * N2 + tc * CPT2 + j];
            #pragma unroll
            for (int i = 0; i < 4; ++i)
                #pragma unroll
                for (int j = 0; j < CPT2; ++j) acc2[i][j] = fmaf(a[i], b[j], acc2[i][j]);
        }
    }

    float bv[CPT2];
    #pragma unroll
    for (int j = 0; j < CPT2; ++j) bv[j] = B2[tc * CPT2 + j];
    #pragma unroll
    for (int i = 0; i < 4; ++i) {
        int m = m0 + tr * 4 + i;
        if (m < nrows) {
            #pragma unroll
            for (int j = 0; j < CPT2; ++j) {
                float v = acc2[i][j] + bv[j];
                v = v > 0.f ? v : 0.01f * v;
                Out[(size_t)m * N2 + tc * CPT2 + j] = v;
            }
        }
    }
}

// ---------------- launch ----------------

extern "C" void kernel_launch(void* const* d_in, const int* in_sizes, int n_in,
                              void* d_out, int out_size, void* d_ws, size_t ws_size,
                              hipStream_t stream) {
    const float* x   = (const float*)d_in[0];
    const int*   src = (const int*)d_in[1];
    const int*   dst = (const int*)d_in[2];
    const float* eps = (const float*)d_in[3];
    const float* w1s = (const float*)d_in[4];
    const float* b1s = (const float*)d_in[5];
    const float* w2s = (const float*)d_in[6];
    const float* b2s = (const float*)d_in[7];
    const float* wf1 = (const float*)d_in[8];
    const float* bf1 = (const float*)d_in[9];
    const float* wf2 = (const float*)d_in[10];
    const float* bf2 = (const float*)d_in[11];

    const int N = in_sizes[0] / NCH;   // 100000
    const int E = in_sizes[1];         // 600000

    auto align256 = [](size_t v) { return (v + 255) & ~(size_t)255; };
    char* p = (char*)d_ws;
    int* off    = (int*)p; p += align256((size_t)(N + 1) * 4);
    int* cursor = (int*)p; p += align256((size_t)N * 4);
    int* csr    = (int*)p; p += align256((size_t)E * 4);
    float* hb   = (float*)p; p += (size_t)N * NCH * 4;
    float* zb   = (float*)p;

    // CSR build (by dst)
    hipMemsetAsync(off, 0, (size_t)(N + 1) * 4, stream);
    gin_deg_kernel<<<(E + 255) / 256, 256, 0, stream>>>(dst, off, E);
    gin_scan_kernel<<<1, 1024, 0, stream>>>(off, N + 1);
    gin_copy_kernel<<<(N + 255) / 256, 256, 0, stream>>>(off, cursor, N);
    gin_fill_kernel<<<(E + 255) / 256, 256, 0, stream>>>(src, dst, cursor, csr, E);

    const int aggGrid = (N + 1) / 2;
    const int mlpGrid = (N + 63) / 64;

    // layer 0 (reads x directly)
    gin_agg_kernel<<<aggGrid, 256, 0, stream>>>(x, off, csr, eps, 0, zb, N);
    gin_mlp_kernel<128, 128><<<mlpGrid, 256, 0, stream>>>(zb, w1s, b1s, w2s, b2s, hb, N);
    // layers 1,2
    for (int l = 1; l < 3; ++l) {
        gin_agg_kernel<<<aggGrid, 256, 0, stream>>>(hb, off, csr, eps, l, zb, N);
        gin_mlp_kernel<128, 128><<<mlpGrid, 256, 0, stream>>>(
            zb, w1s + (size_t)l * 128 * 128, b1s + (size_t)l * 128,
            w2s + (size_t)l * 128 * 128, b2s + (size_t)l * 128, hb, N);
    }
    // final GINConv: 128 -> 64 -> 64, writes d_out
    gin_agg_kernel<<<aggGrid, 256, 0, stream>>>(hb, off, csr, eps, 3, zb, N);
    gin_mlp_kernel<64, 64><<<mlpGrid, 256, 0, stream>>>(
        zb, wf1, bf1, wf2, bf2, (float*)d_out, N);
}

// Round 2
// 646.869 us; speedup vs baseline: 1.9963x; 1.9963x over previous
//
#include <hip/hip_runtime.h>

#define NCH 128

typedef short bf16x8 __attribute__((ext_vector_type(8)));
typedef float f32x4 __attribute__((ext_vector_type(4)));

__device__ __forceinline__ unsigned short f32_to_bf16_rne(float f) {
    unsigned u = __float_as_uint(f);
    unsigned r = u + 0x7FFFu + ((u >> 16) & 1u);
    return (unsigned short)(r >> 16);
}
__device__ __forceinline__ float bf16_hi_part(float f) {
    unsigned u = __float_as_uint(f);
    unsigned r = (u + 0x7FFFu + ((u >> 16) & 1u)) & 0xFFFF0000u;
    return __uint_as_float(r);
}

// ---------------- CSR build ----------------
// off[d] ends as EXCLUSIVE prefix (start index of node d) after scan;
// fill atomically bumps off[d] so afterwards off[d] = inclusive end of node d.

__global__ void gin_deg_kernel(const int* __restrict__ dst, int* __restrict__ off, int E) {
    int e = blockIdx.x * 256 + threadIdx.x;
    if (e < E) atomicAdd(&off[dst[e] + 1], 1);
}

__global__ void gin_scan_kernel(int* __restrict__ off, int n) {
    __shared__ int part[1024];
    int t = threadIdx.x;
    int chunk = (n + 1023) / 1024;
    int lo = t * chunk;
    int hi = min(lo + chunk, n);
    int s = 0;
    for (int i = lo; i < hi; ++i) s += off[i];
    part[t] = s;
    __syncthreads();
    for (int o = 1; o < 1024; o <<= 1) {
        int v = (t >= o) ? part[t - o] : 0;
        __syncthreads();
        part[t] += v;
        __syncthreads();
    }
    int run = (t == 0) ? 0 : part[t - 1];
    for (int i = lo; i < hi; ++i) { run += off[i]; off[i] = run; }
}

__global__ void gin_fill_kernel(const int* __restrict__ src, const int* __restrict__ dst,
                                int* __restrict__ off, int* __restrict__ csr, int E) {
    int e = blockIdx.x * 256 + threadIdx.x;
    if (e < E) {
        int d = dst[e];
        int p = atomicAdd(&off[d], 1);
        csr[p] = src[e];
    }
}

// ---------------- weight pre-pack into MFMA B-fragment order (bf16 hi/lo) ----------------
// out[(((spl*(K/32)+kc)*(N/16)+nt)*64+l)*8+j] = split_spl( W[kc*32+(l>>4)*8+j][nt*16+(l&15)] )
__global__ void gin_pack_kernel(const float* __restrict__ W, int K, int N,
                                unsigned short* __restrict__ out) {
    int idx = blockIdx.x * 256 + threadIdx.x;
    int KC = K / 32, NT = N / 16;
    int total = 2 * KC * NT * 64 * 8;
    if (idx >= total) return;
    int j = idx & 7;
    int l = (idx >> 3) & 63;
    int v = idx >> 9;
    int nt = v % NT; v /= NT;
    int kc = v % KC;
    int spl = v / KC;
    int k = kc * 32 + (l >> 4) * 8 + j;
    int n = nt * 16 + (l & 15);
    float w = W[(size_t)k * N + n];
    if (spl == 0) {
        out[idx] = f32_to_bf16_rne(w);
    } else {
        float lo = w - bf16_hi_part(w);
        out[idx] = f32_to_bf16_rne(lo);
    }
}

// ---------------- aggregation: z = (1+eps)*h + mean_neigh -> (zh, zl) bf16 split ----------------
// 8 nodes per 256-thread block; 32 lanes x float4 per node.
__global__ __launch_bounds__(256)
void gin_agg_kernel(const float* __restrict__ h, const int* __restrict__ offend,
                    const int* __restrict__ csr, const float* __restrict__ eps, int layer,
                    unsigned short* __restrict__ zh, unsigned short* __restrict__ zl, int n) {
    int node = blockIdx.x * 8 + (threadIdx.x >> 5);
    if (node >= n) return;
    int lane = threadIdx.x & 31;
    int lo = node ? offend[node - 1] : 0;
    int hi = offend[node];

    float s0 = 0.f, s1 = 0.f, s2 = 0.f, s3 = 0.f;
    float t0 = 0.f, t1 = 0.f, t2 = 0.f, t3 = 0.f;
    int e = lo;
    for (; e + 1 < hi; e += 2) {
        int a = csr[e], b = csr[e + 1];
        const float4 va = *(const float4*)(h + (size_t)a * NCH + lane * 4);
        const float4 vb = *(const float4*)(h + (size_t)b * NCH + lane * 4);
        s0 += va.x; s1 += va.y; s2 += va.z; s3 += va.w;
        t0 += vb.x; t1 += vb.y; t2 += vb.z; t3 += vb.w;
    }
    if (e < hi) {
        int a = csr[e];
        const float4 va = *(const float4*)(h + (size_t)a * NCH + lane * 4);
        s0 += va.x; s1 += va.y; s2 += va.z; s3 += va.w;
    }
    float invd = 1.0f / fmaxf((float)(hi - lo), 1.0f);
    const float4 self = *(const float4*)(h + (size_t)node * NCH + lane * 4);
    float e1 = 1.0f + eps[layer];
    float z0 = e1 * self.x + (s0 + t0) * invd;
    float z1 = e1 * self.y + (s1 + t1) * invd;
    float z2 = e1 * self.z + (s2 + t2) * invd;
    float z3 = e1 * self.w + (s3 + t3) * invd;

    ushort4 hv, lv;
    hv.x = f32_to_bf16_rne(z0); lv.x = f32_to_bf16_rne(z0 - bf16_hi_part(z0));
    hv.y = f32_to_bf16_rne(z1); lv.y = f32_to_bf16_rne(z1 - bf16_hi_part(z1));
    hv.z = f32_to_bf16_rne(z2); lv.z = f32_to_bf16_rne(z2 - bf16_hi_part(z2));
    hv.w = f32_to_bf16_rne(z3); lv.w = f32_to_bf16_rne(z3 - bf16_hi_part(z3));
    *(ushort4*)(zh + (size_t)node * NCH + lane * 4) = hv;
    *(ushort4*)(zl + (size_t)node * NCH + lane * 4) = lv;
}

// ---------------- fused 2-GEMM MLP on matrix cores (split-bf16, 3 MFMA terms) ----------------
// Block: 128 threads (2 waves), 64 rows. Wave w owns rows w*32..w*32+31 (2 row-tiles),
// all N columns. T bounces through padded LDS per-wave region; one barrier.
template <int N1, int N2>
__global__ __launch_bounds__(128)
void gin_mlp_mfma(const unsigned short* __restrict__ Zh, const unsigned short* __restrict__ Zl,
                  const unsigned short* __restrict__ PW1, const float* __restrict__ B1,
                  const unsigned short* __restrict__ PW2, const float* __restrict__ B2,
                  float* __restrict__ Out, int nrows) {
    constexpr int K1 = 128;
    constexpr int KC1 = K1 / 32, NT1 = N1 / 16, KC2 = N1 / 32, NT2 = N2 / 16;
    constexpr int TS = N1 + 4;  // f32 row stride: (row*TS+col) mod 32 = 4*row+col -> <=2-way
    __shared__ __align__(16) float Tlds[64 * TS];

    const int tid = threadIdx.x;
    const int w = tid >> 6;   // 0..1
    const int l = tid & 63;
    const int lr = l & 15;    // row (A) / col (B) within tile
    const int lg = l >> 4;    // k-group
    const int m0 = blockIdx.x * 64;
    const int wrow = w * 32;

    f32x4 acc[2][NT1];
    #pragma unroll
    for (int rt = 0; rt < 2; ++rt)
        #pragma unroll
        for (int nt = 0; nt < NT1; ++nt) acc[rt][nt] = {0.f, 0.f, 0.f, 0.f};

    // ---- GEMM1: T = leaky(Z @ W1 + b1) ----
    #pragma unroll
    for (int kc = 0; kc < KC1; ++kc) {
        bf16x8 ah[2], al[2];
        #pragma unroll
        for (int rt = 0; rt < 2; ++rt) {
            int row = m0 + wrow + rt * 16 + lr;
            if (row < nrows) {
                size_t zo = (size_t)row * K1 + kc * 32 + lg * 8;
                ah[rt] = *(const bf16x8*)(Zh + zo);
                al[rt] = *(const bf16x8*)(Zl + zo);
            } else {
                ah[rt] = (bf16x8){0,0,0,0,0,0,0,0};
                al[rt] = (bf16x8){0,0,0,0,0,0,0,0};
            }
        }
        #pragma unroll
        for (int nt = 0; nt < NT1; ++nt) {
            const unsigned short* pb = PW1 + (((size_t)kc * NT1 + nt) * 64 + l) * 8;
            bf16x8 bh = *(const bf16x8*)pb;
            bf16x8 bl = *(const bf16x8*)(pb + (size_t)KC1 * NT1 * 512);
            #pragma unroll
            for (int rt = 0; rt < 2; ++rt) {
                acc[rt][nt] = __builtin_amdgcn_mfma_f32_16x16x32_bf16(ah[rt], bh, acc[rt][nt], 0, 0, 0);
                acc[rt][nt] = __builtin_amdgcn_mfma_f32_16x16x32_bf16(ah[rt], bl, acc[rt][nt], 0, 0, 0);
                acc[rt][nt] = __builtin_amdgcn_mfma_f32_16x16x32_bf16(al[rt], bh, acc[rt][nt], 0, 0, 0);
            }
        }
    }

    // epilogue 1: bias + leaky -> LDS (C/D layout: row=lg*4+r, col=lr)
    #pragma unroll
    for (int nt = 0; nt < NT1; ++nt) {
        float bb = B1[nt * 16 + lr];
        #pragma unroll
        for (int rt = 0; rt < 2; ++rt)
            #pragma unroll
            for (int r = 0; r < 4; ++r) {
                float v = acc[rt][nt][r] + bb;
                v = v > 0.f ? v : 0.01f * v;
                Tlds[(wrow + rt * 16 + lg * 4 + r) * TS + nt * 16 + lr] = v;
            }
    }
    __syncthreads();

    // ---- GEMM2: out = leaky(T @ W2 + b2) ----
    f32x4 acc2[2][NT2];
    #pragma unroll
    for (int rt = 0; rt < 2; ++rt)
        #pragma unroll
        for (int nt = 0; nt < NT2; ++nt) acc2[rt][nt] = {0.f, 0.f, 0.f, 0.f};

    #pragma unroll
    for (int kc = 0; kc < KC2; ++kc) {
        bf16x8 ah[2], al[2];
        #pragma unroll
        for (int rt = 0; rt < 2; ++rt) {
            const float* tp = &Tlds[(wrow + rt * 16 + lr) * TS + kc * 32 + lg * 8];
            f32x4 v0 = *(const f32x4*)tp;
            f32x4 v1 = *(const f32x4*)(tp + 4);
            union { bf16x8 v; unsigned short u[8]; } H, L;
            #pragma unroll
            for (int i = 0; i < 4; ++i) {
                H.u[i] = f32_to_bf16_rne(v0[i]);
                L.u[i] = f32_to_bf16_rne(v0[i] - bf16_hi_part(v0[i]));
                H.u[i + 4] = f32_to_bf16_rne(v1[i]);
                L.u[i + 4] = f32_to_bf16_rne(v1[i] - bf16_hi_part(v1[i]));
            }
            ah[rt] = H.v; al[rt] = L.v;
        }
        #pragma unroll
        for (int nt = 0; nt < NT2; ++nt) {
            const unsigned short* pb = PW2 + (((size_t)kc * NT2 + nt) * 64 + l) * 8;
            bf16x8 bh = *(const bf16x8*)pb;
            bf16x8 bl = *(const bf16x8*)(pb + (size_t)KC2 * NT2 * 512);
            #pragma unroll
            for (int rt = 0; rt < 2; ++rt) {
                acc2[rt][nt] = __builtin_amdgcn_mfma_f32_16x16x32_bf16(ah[rt], bh, acc2[rt][nt], 0, 0, 0);
                acc2[rt][nt] = __builtin_amdgcn_mfma_f32_16x16x32_bf16(ah[rt], bl, acc2[rt][nt], 0, 0, 0);
                acc2[rt][nt] = __builtin_amdgcn_mfma_f32_16x16x32_bf16(al[rt], bh, acc2[rt][nt], 0, 0, 0);
            }
        }
    }

    // epilogue 2: bias + leaky -> global
    #pragma unroll
    for (int nt = 0; nt < NT2; ++nt) {
        float bb = B2[nt * 16 + lr];
        #pragma unroll
        for (int rt = 0; rt < 2; ++rt)
            #pragma unroll
            for (int r = 0; r < 4; ++r) {
                int row = m0 + wrow + rt * 16 + lg * 4 + r;
                if (row < nrows) {
                    float v = acc2[rt][nt][r] + bb;
                    v = v > 0.f ? v : 0.01f * v;
                    Out[(size_t)row * N2 + nt * 16 + lr] = v;
                }
            }
    }
}

// ---------------- launch ----------------

extern "C" void kernel_launch(void* const* d_in, const int* in_sizes, int n_in,
                              void* d_out, int out_size, void* d_ws, size_t ws_size,
                              hipStream_t stream) {
    const float* x   = (const float*)d_in[0];
    const int*   src = (const int*)d_in[1];
    const int*   dst = (const int*)d_in[2];
    const float* eps = (const float*)d_in[3];
    const float* w1s = (const float*)d_in[4];
    const float* b1s = (const float*)d_in[5];
    const float* w2s = (const float*)d_in[6];
    const float* b2s = (const float*)d_in[7];
    const float* wf1 = (const float*)d_in[8];
    const float* bf1 = (const float*)d_in[9];
    const float* wf2 = (const float*)d_in[10];
    const float* bf2 = (const float*)d_in[11];

    const int N = in_sizes[0] / NCH;   // 100000
    const int E = in_sizes[1];         // 600000

    auto align256 = [](size_t v) { return (v + 255) & ~(size_t)255; };
    char* p = (char*)d_ws;
    int* off = (int*)p;             p += align256((size_t)(N + 1) * 4);
    int* csr = (int*)p;             p += align256((size_t)E * 4);
    float* hb = (float*)p;          p += (size_t)N * NCH * 4;
    unsigned short* zh = (unsigned short*)p; p += (size_t)N * NCH * 2;
    unsigned short* zl = (unsigned short*)p; p += (size_t)N * NCH * 2;
    unsigned short* pw1 = (unsigned short*)p; p += 3 * 65536;
    unsigned short* pw2 = (unsigned short*)p; p += 3 * 65536;
    unsigned short* pwf1 = (unsigned short*)p; p += 32768;
    unsigned short* pwf2 = (unsigned short*)p;

    // CSR build
    hipMemsetAsync(off, 0, (size_t)(N + 1) * 4, stream);
    gin_deg_kernel<<<(E + 255) / 256, 256, 0, stream>>>(dst, off, E);
    gin_scan_kernel<<<1, 1024, 0, stream>>>(off, N + 1);
    gin_fill_kernel<<<(E + 255) / 256, 256, 0, stream>>>(src, dst, off, csr, E);

    // pack weights (bf16 hi/lo fragment order)
    for (int layer = 0; layer < 3; ++layer) {
        gin_pack_kernel<<<128, 256, 0, stream>>>(w1s + (size_t)layer * 128 * 128, 128, 128,
                                                 (unsigned short*)((char*)pw1 + (size_t)layer * 65536));
        gin_pack_kernel<<<128, 256, 0, stream>>>(w2s + (size_t)layer * 128 * 128, 128, 128,
                                                 (unsigned short*)((char*)pw2 + (size_t)layer * 65536));
    }
    gin_pack_kernel<<<64, 256, 0, stream>>>(wf1, 128, 64, pwf1);
    gin_pack_kernel<<<32, 256, 0, stream>>>(wf2, 64, 64, pwf2);

    const int aggGrid = (N + 7) / 8;
    const int mlpGrid = (N + 63) / 64;

    gin_agg_kernel<<<aggGrid, 256, 0, stream>>>(x, off, csr, eps, 0, zh, zl, N);
    gin_mlp_mfma<128, 128><<<mlpGrid, 128, 0, stream>>>(
        zh, zl, pw1, b1s, pw2, b2s, hb, N);
    for (int layer = 1; layer < 3; ++layer) {
        gin_agg_kernel<<<aggGrid, 256, 0, stream>>>(hb, off, csr, eps, layer, zh, zl, N);
        gin_mlp_mfma<128, 128><<<mlpGrid, 128, 0, stream>>>(
            zh, zl,
            (unsigned short*)((char*)pw1 + (size_t)layer * 65536), b1s + (size_t)layer * 128,
            (unsigned short*)((char*)pw2 + (size_t)layer * 65536), b2s + (size_t)layer * 128,
            hb, N);
    }
    gin_agg_kernel<<<aggGrid, 256, 0, stream>>>(hb, off, csr, eps, 3, zh, zl, N);
    gin_mlp_mfma<64, 64><<<mlpGrid, 128, 0, stream>>>(
        zh, zl, pwf1, bf1, pwf2, bf2, (float*)d_out, N);
}

// Round 3
// 496.660 us; speedup vs baseline: 2.6001x; 1.3024x over previous
//
#include <hip/hip_runtime.h>

#define NCH 128

typedef short bf16x8 __attribute__((ext_vector_type(8)));
typedef float f32x4 __attribute__((ext_vector_type(4)));

__device__ __forceinline__ unsigned short f32_to_bf16_rne(float f) {
    unsigned u = __float_as_uint(f);
    unsigned r = u + 0x7FFFu + ((u >> 16) & 1u);
    return (unsigned short)(r >> 16);
}
__device__ __forceinline__ float bf16_hi_part(float f) {
    unsigned u = __float_as_uint(f);
    unsigned r = (u + 0x7FFFu + ((u >> 16) & 1u)) & 0xFFFF0000u;
    return __uint_as_float(r);
}

// ---------------- CSR build ----------------
// After deg+scan: off[d] = start index of node d (exclusive prefix of degrees).
// fill atomically bumps off[d]; afterwards off[d] = inclusive END of node d.

__global__ void gin_deg_kernel(const int* __restrict__ dst, int* __restrict__ off, int E) {
    int e = blockIdx.x * 256 + threadIdx.x;
    if (e < E) atomicAdd(&off[dst[e] + 1], 1);
}

// hierarchical inclusive scan over off[0..n-1], tiles of 2048
__global__ void gin_scan1(const int* __restrict__ off, int* __restrict__ part, int n) {
    __shared__ int red[256];
    int t = threadIdx.x;
    int base = blockIdx.x * 2048 + t * 8;
    int s = 0;
    if (base + 8 <= n) {
        #pragma unroll
        for (int i = 0; i < 8; ++i) s += off[base + i];
    } else {
        for (int i = 0; i < 8; ++i) { int idx = base + i; if (idx < n) s += off[idx]; }
    }
    red[t] = s;
    __syncthreads();
    #pragma unroll
    for (int o = 128; o > 0; o >>= 1) {
        if (t < o) red[t] += red[t + o];
        __syncthreads();
    }
    if (t == 0) part[blockIdx.x] = red[0];
}

__global__ void gin_scan2(int* __restrict__ part, int nb) {
    __shared__ int sh[256];
    int t = threadIdx.x;
    int v = (t < nb) ? part[t] : 0;
    sh[t] = v;
    __syncthreads();
    #pragma unroll
    for (int o = 1; o < 256; o <<= 1) {
        int u = (t >= o) ? sh[t - o] : 0;
        __syncthreads();
        sh[t] += u;
        __syncthreads();
    }
    if (t < nb) part[t] = sh[t] - v;  // exclusive block offsets
}

__global__ void gin_scan3(int* __restrict__ off, const int* __restrict__ part, int n) {
    __shared__ int red[256];
    int t = threadIdx.x;
    int base = blockIdx.x * 2048 + t * 8;
    int loc[8];
    int s = 0;
    #pragma unroll
    for (int i = 0; i < 8; ++i) {
        int idx = base + i;
        int v = (idx < n) ? off[idx] : 0;
        s += v;
        loc[i] = s;  // inclusive within thread
    }
    red[t] = s;
    __syncthreads();
    #pragma unroll
    for (int o = 1; o < 256; o <<= 1) {
        int u = (t >= o) ? red[t - o] : 0;
        __syncthreads();
        red[t] += u;
        __syncthreads();
    }
    int offset = part[blockIdx.x] + red[t] - s;  // block base + exclusive thread offset
    #pragma unroll
    for (int i = 0; i < 8; ++i) {
        int idx = base + i;
        if (idx < n) off[idx] = loc[i] + offset;
    }
}

__global__ void gin_fill_kernel(const int* __restrict__ src, const int* __restrict__ dst,
                                int* __restrict__ off, int* __restrict__ csr, int E) {
    int e = blockIdx.x * 256 + threadIdx.x;
    if (e < E) {
        int d = dst[e];
        int p = atomicAdd(&off[d], 1);
        csr[p] = src[e];
    }
}

// ---------------- weight pre-pack into MFMA B-fragment order (bf16 hi/lo) ----------------
__global__ void gin_pack_kernel(const float* __restrict__ W, int K, int N,
                                unsigned short* __restrict__ out) {
    int idx = blockIdx.x * 256 + threadIdx.x;
    int KC = K / 32, NT = N / 16;
    int total = 2 * KC * NT * 64 * 8;
    if (idx >= total) return;
    int j = idx & 7;
    int l = (idx >> 3) & 63;
    int v = idx >> 9;
    int nt = v % NT; v /= NT;
    int kc = v % KC;
    int spl = v / KC;
    int k = kc * 32 + (l >> 4) * 8 + j;
    int n = nt * 16 + (l & 15);
    float w = W[(size_t)k * N + n];
    if (spl == 0) {
        out[idx] = f32_to_bf16_rne(w);
    } else {
        float lo = w - bf16_hi_part(w);
        out[idx] = f32_to_bf16_rne(lo);
    }
}

// ---------------- aggregation: z = (1+eps)*h + mean_neigh -> (zh, zl) bf16 split ----------------
__global__ __launch_bounds__(256)
void gin_agg_kernel(const float* __restrict__ h, const int* __restrict__ offend,
                    const int* __restrict__ csr, const float* __restrict__ eps, int layer,
                    unsigned short* __restrict__ zh, unsigned short* __restrict__ zl, int n) {
    int node = blockIdx.x * 8 + (threadIdx.x >> 5);
    if (node >= n) return;
    int lane = threadIdx.x & 31;
    int lo = node ? offend[node - 1] : 0;
    int hi = offend[node];

    float s0 = 0.f, s1 = 0.f, s2 = 0.f, s3 = 0.f;
    float t0 = 0.f, t1 = 0.f, t2 = 0.f, t3 = 0.f;
    int e = lo;
    for (; e + 1 < hi; e += 2) {
        int a = csr[e], b = csr[e + 1];
        const float4 va = *(const float4*)(h + (size_t)a * NCH + lane * 4);
        const float4 vb = *(const float4*)(h + (size_t)b * NCH + lane * 4);
        s0 += va.x; s1 += va.y; s2 += va.z; s3 += va.w;
        t0 += vb.x; t1 += vb.y; t2 += vb.z; t3 += vb.w;
    }
    if (e < hi) {
        int a = csr[e];
        const float4 va = *(const float4*)(h + (size_t)a * NCH + lane * 4);
        s0 += va.x; s1 += va.y; s2 += va.z; s3 += va.w;
    }
    float invd = 1.0f / fmaxf((float)(hi - lo), 1.0f);
    const float4 self = *(const float4*)(h + (size_t)node * NCH + lane * 4);
    float e1 = 1.0f + eps[layer];
    float z0 = e1 * self.x + (s0 + t0) * invd;
    float z1 = e1 * self.y + (s1 + t1) * invd;
    float z2 = e1 * self.z + (s2 + t2) * invd;
    float z3 = e1 * self.w + (s3 + t3) * invd;

    ushort4 hv, lv;
    hv.x = f32_to_bf16_rne(z0); lv.x = f32_to_bf16_rne(z0 - bf16_hi_part(z0));
    hv.y = f32_to_bf16_rne(z1); lv.y = f32_to_bf16_rne(z1 - bf16_hi_part(z1));
    hv.z = f32_to_bf16_rne(z2); lv.z = f32_to_bf16_rne(z2 - bf16_hi_part(z2));
    hv.w = f32_to_bf16_rne(z3); lv.w = f32_to_bf16_rne(z3 - bf16_hi_part(z3));
    *(ushort4*)(zh + (size_t)node * NCH + lane * 4) = hv;
    *(ushort4*)(zl + (size_t)node * NCH + lane * 4) = lv;
}

// ---------------- fused 2-GEMM MLP on matrix cores (split-bf16, 3 MFMA terms) ----------------
template <int N1, int N2>
__global__ __launch_bounds__(128)
void gin_mlp_mfma(const unsigned short* __restrict__ Zh, const unsigned short* __restrict__ Zl,
                  const unsigned short* __restrict__ PW1, const float* __restrict__ B1,
                  const unsigned short* __restrict__ PW2, const float* __restrict__ B2,
                  float* __restrict__ Out, int nrows) {
    constexpr int K1 = 128;
    constexpr int KC1 = K1 / 32, NT1 = N1 / 16, KC2 = N1 / 32, NT2 = N2 / 16;
    constexpr int TS = N1 + 4;
    __shared__ __align__(16) float Tlds[64 * TS];

    const int tid = threadIdx.x;
    const int w = tid >> 6;
    const int l = tid & 63;
    const int lr = l & 15;
    const int lg = l >> 4;
    const int m0 = blockIdx.x * 64;
    const int wrow = w * 32;

    f32x4 acc[2][NT1];
    #pragma unroll
    for (int rt = 0; rt < 2; ++rt)
        #pragma unroll
        for (int nt = 0; nt < NT1; ++nt) acc[rt][nt] = {0.f, 0.f, 0.f, 0.f};

    // ---- GEMM1: T = leaky(Z @ W1 + b1) ----
    #pragma unroll
    for (int kc = 0; kc < KC1; ++kc) {
        bf16x8 ah[2], al[2];
        #pragma unroll
        for (int rt = 0; rt < 2; ++rt) {
            int row = m0 + wrow + rt * 16 + lr;
            if (row < nrows) {
                size_t zo = (size_t)row * K1 + kc * 32 + lg * 8;
                ah[rt] = *(const bf16x8*)(Zh + zo);
                al[rt] = *(const bf16x8*)(Zl + zo);
            } else {
                ah[rt] = (bf16x8){0,0,0,0,0,0,0,0};
                al[rt] = (bf16x8){0,0,0,0,0,0,0,0};
            }
        }
        #pragma unroll
        for (int nt = 0; nt < NT1; ++nt) {
            const unsigned short* pb = PW1 + (((size_t)kc * NT1 + nt) * 64 + l) * 8;
            bf16x8 bh = *(const bf16x8*)pb;
            bf16x8 bl = *(const bf16x8*)(pb + (size_t)KC1 * NT1 * 512);
            #pragma unroll
            for (int rt = 0; rt < 2; ++rt) {
                acc[rt][nt] = __builtin_amdgcn_mfma_f32_16x16x32_bf16(ah[rt], bh, acc[rt][nt], 0, 0, 0);
                acc[rt][nt] = __builtin_amdgcn_mfma_f32_16x16x32_bf16(ah[rt], bl, acc[rt][nt], 0, 0, 0);
                acc[rt][nt] = __builtin_amdgcn_mfma_f32_16x16x32_bf16(al[rt], bh, acc[rt][nt], 0, 0, 0);
            }
        }
    }

    // epilogue 1: bias + leaky -> LDS (C/D layout: row=lg*4+r, col=lr)
    #pragma unroll
    for (int nt = 0; nt < NT1; ++nt) {
        float bb = B1[nt * 16 + lr];
        #pragma unroll
        for (int rt = 0; rt < 2; ++rt)
            #pragma unroll
            for (int r = 0; r < 4; ++r) {
                float v = acc[rt][nt][r] + bb;
                v = v > 0.f ? v : 0.01f * v;
                Tlds[(wrow + rt * 16 + lg * 4 + r) * TS + nt * 16 + lr] = v;
            }
    }
    __syncthreads();

    // ---- GEMM2: out = leaky(T @ W2 + b2) ----
    f32x4 acc2[2][NT2];
    #pragma unroll
    for (int rt = 0; rt < 2; ++rt)
        #pragma unroll
        for (int nt = 0; nt < NT2; ++nt) acc2[rt][nt] = {0.f, 0.f, 0.f, 0.f};

    #pragma unroll
    for (int kc = 0; kc < KC2; ++kc) {
        bf16x8 ah[2], al[2];
        #pragma unroll
        for (int rt = 0; rt < 2; ++rt) {
            const float* tp = &Tlds[(wrow + rt * 16 + lr) * TS + kc * 32 + lg * 8];
            f32x4 v0 = *(const f32x4*)tp;
            f32x4 v1 = *(const f32x4*)(tp + 4);
            union { bf16x8 v; unsigned short u[8]; } H, L;
            #pragma unroll
            for (int i = 0; i < 4; ++i) {
                H.u[i] = f32_to_bf16_rne(v0[i]);
                L.u[i] = f32_to_bf16_rne(v0[i] - bf16_hi_part(v0[i]));
                H.u[i + 4] = f32_to_bf16_rne(v1[i]);
                L.u[i + 4] = f32_to_bf16_rne(v1[i] - bf16_hi_part(v1[i]));
            }
            ah[rt] = H.v; al[rt] = L.v;
        }
        #pragma unroll
        for (int nt = 0; nt < NT2; ++nt) {
            const unsigned short* pb = PW2 + (((size_t)kc * NT2 + nt) * 64 + l) * 8;
            bf16x8 bh = *(const bf16x8*)pb;
            bf16x8 bl = *(const bf16x8*)(pb + (size_t)KC2 * NT2 * 512);
            #pragma unroll
            for (int rt = 0; rt < 2; ++rt) {
                acc2[rt][nt] = __builtin_amdgcn_mfma_f32_16x16x32_bf16(ah[rt], bh, acc2[rt][nt], 0, 0, 0);
                acc2[rt][nt] = __builtin_amdgcn_mfma_f32_16x16x32_bf16(ah[rt], bl, acc2[rt][nt], 0, 0, 0);
                acc2[rt][nt] = __builtin_amdgcn_mfma_f32_16x16x32_bf16(al[rt], bh, acc2[rt][nt], 0, 0, 0);
            }
        }
    }

    // epilogue 2: bias + leaky -> global
    #pragma unroll
    for (int nt = 0; nt < NT2; ++nt) {
        float bb = B2[nt * 16 + lr];
        #pragma unroll
        for (int rt = 0; rt < 2; ++rt)
            #pragma unroll
            for (int r = 0; r < 4; ++r) {
                int row = m0 + wrow + rt * 16 + lg * 4 + r;
                if (row < nrows) {
                    float v = acc2[rt][nt][r] + bb;
                    v = v > 0.f ? v : 0.01f * v;
                    Out[(size_t)row * N2 + nt * 16 + lr] = v;
                }
            }
    }
}

// ---------------- launch ----------------

extern "C" void kernel_launch(void* const* d_in, const int* in_sizes, int n_in,
                              void* d_out, int out_size, void* d_ws, size_t ws_size,
                              hipStream_t stream) {
    const float* x   = (const float*)d_in[0];
    const int*   src = (const int*)d_in[1];
    const int*   dst = (const int*)d_in[2];
    const float* eps = (const float*)d_in[3];
    const float* w1s = (const float*)d_in[4];
    const float* b1s = (const float*)d_in[5];
    const float* w2s = (const float*)d_in[6];
    const float* b2s = (const float*)d_in[7];
    const float* wf1 = (const float*)d_in[8];
    const float* bf1 = (const float*)d_in[9];
    const float* wf2 = (const float*)d_in[10];
    const float* bf2 = (const float*)d_in[11];

    const int N = in_sizes[0] / NCH;   // 100000
    const int E = in_sizes[1];         // 600000

    auto align256 = [](size_t v) { return (v + 255) & ~(size_t)255; };
    char* p = (char*)d_ws;
    int* off = (int*)p;             p += align256((size_t)(N + 1) * 4);
    int* part = (int*)p;            p += align256(1024 * 4);
    int* csr = (int*)p;             p += align256((size_t)E * 4);
    float* hb = (float*)p;          p += (size_t)N * NCH * 4;
    unsigned short* zh = (unsigned short*)p; p += (size_t)N * NCH * 2;
    unsigned short* zl = (unsigned short*)p; p += (size_t)N * NCH * 2;
    unsigned short* pw1 = (unsigned short*)p; p += 3 * 65536;
    unsigned short* pw2 = (unsigned short*)p; p += 3 * 65536;
    unsigned short* pwf1 = (unsigned short*)p; p += 32768;
    unsigned short* pwf2 = (unsigned short*)p;

    // CSR build
    const int nScan = N + 1;
    const int nTiles = (nScan + 2047) / 2048;   // 49 for N=100000
    hipMemsetAsync(off, 0, (size_t)nScan * 4, stream);
    gin_deg_kernel<<<(E + 255) / 256, 256, 0, stream>>>(dst, off, E);
    gin_scan1<<<nTiles, 256, 0, stream>>>(off, part, nScan);
    gin_scan2<<<1, 256, 0, stream>>>(part, nTiles);
    gin_scan3<<<nTiles, 256, 0, stream>>>(off, part, nScan);
    gin_fill_kernel<<<(E + 255) / 256, 256, 0, stream>>>(src, dst, off, csr, E);

    // pack weights (bf16 hi/lo fragment order)
    for (int layer = 0; layer < 3; ++layer) {
        gin_pack_kernel<<<128, 256, 0, stream>>>(w1s + (size_t)layer * 128 * 128, 128, 128,
                                                 (unsigned short*)((char*)pw1 + (size_t)layer * 65536));
        gin_pack_kernel<<<128, 256, 0, stream>>>(w2s + (size_t)layer * 128 * 128, 128, 128,
                                                 (unsigned short*)((char*)pw2 + (size_t)layer * 65536));
    }
    gin_pack_kernel<<<64, 256, 0, stream>>>(wf1, 128, 64, pwf1);
    gin_pack_kernel<<<32, 256, 0, stream>>>(wf2, 64, 64, pwf2);

    const int aggGrid = (N + 7) / 8;
    const int mlpGrid = (N + 63) / 64;

    gin_agg_kernel<<<aggGrid, 256, 0, stream>>>(x, off, csr, eps, 0, zh, zl, N);
    gin_mlp_mfma<128, 128><<<mlpGrid, 128, 0, stream>>>(
        zh, zl, pw1, b1s, pw2, b2s, hb, N);
    for (int layer = 1; layer < 3; ++layer) {
        gin_agg_kernel<<<aggGrid, 256, 0, stream>>>(hb, off, csr, eps, layer, zh, zl, N);
        gin_mlp_mfma<128, 128><<<mlpGrid, 128, 0, stream>>>(
            zh, zl,
            (unsigned short*)((char*)pw1 + (size_t)layer * 65536), b1s + (size_t)layer * 128,
            (unsigned short*)((char*)pw2 + (size_t)layer * 65536), b2s + (size_t)layer * 128,
            hb, N);
    }
    gin_agg_kernel<<<aggGrid, 256, 0, stream>>>(hb, off, csr, eps, 3, zh, zl, N);
    gin_mlp_mfma<64, 64><<<mlpGrid, 128, 0, stream>>>(
        zh, zl, pwf1, bf1, pwf2, bf2, (float*)d_out, N);
}

// Round 4
// 468.962 us; speedup vs baseline: 2.7537x; 1.0591x over previous
//
#include <hip/hip_runtime.h>
#include <hip/hip_fp16.h>

#define NCH 128

typedef short bf16x8 __attribute__((ext_vector_type(8)));
typedef float f32x4 __attribute__((ext_vector_type(4)));

__device__ __forceinline__ unsigned short f32_to_bf16_rne(float f) {
    unsigned u = __float_as_uint(f);
    unsigned r = u + 0x7FFFu + ((u >> 16) & 1u);
    return (unsigned short)(r >> 16);
}
__device__ __forceinline__ float bf16_trunc_part(float f) {
    return __uint_as_float(__float_as_uint(f) & 0xFFFF0000u);
}
// trunc-split: hi = trunc16(f), lo = rne(f - hi). |lo| <= 2^-8|f|, exactness preserved.
__device__ __forceinline__ void split_bf16(float f, unsigned short& hi, unsigned short& lo) {
    unsigned u = __float_as_uint(f);
    hi = (unsigned short)(u >> 16);
    float l = f - __uint_as_float(u & 0xFFFF0000u);
    lo = f32_to_bf16_rne(l);
}

// ---------------- CSR build ----------------
// After deg+scan: off[d] = start of node d. fill bumps off[d]; after: off[d] = inclusive end.

__global__ void gin_deg_kernel(const int* __restrict__ dst, int* __restrict__ off, int E) {
    int e = blockIdx.x * 256 + threadIdx.x;
    if (e < E) atomicAdd(&off[dst[e] + 1], 1);
}

__global__ void gin_scan1(const int* __restrict__ off, int* __restrict__ part, int n) {
    __shared__ int red[256];
    int t = threadIdx.x;
    int base = blockIdx.x * 2048 + t * 8;
    int s = 0;
    if (base + 8 <= n) {
        #pragma unroll
        for (int i = 0; i < 8; ++i) s += off[base + i];
    } else {
        for (int i = 0; i < 8; ++i) { int idx = base + i; if (idx < n) s += off[idx]; }
    }
    red[t] = s;
    __syncthreads();
    #pragma unroll
    for (int o = 128; o > 0; o >>= 1) {
        if (t < o) red[t] += red[t + o];
        __syncthreads();
    }
    if (t == 0) part[blockIdx.x] = red[0];
}

__global__ void gin_scan2(int* __restrict__ part, int nb) {
    __shared__ int sh[256];
    int t = threadIdx.x;
    int v = (t < nb) ? part[t] : 0;
    sh[t] = v;
    __syncthreads();
    #pragma unroll
    for (int o = 1; o < 256; o <<= 1) {
        int u = (t >= o) ? sh[t - o] : 0;
        __syncthreads();
        sh[t] += u;
        __syncthreads();
    }
    if (t < nb) part[t] = sh[t] - v;
}

__global__ void gin_scan3(int* __restrict__ off, const int* __restrict__ part, int n) {
    __shared__ int red[256];
    int t = threadIdx.x;
    int base = blockIdx.x * 2048 + t * 8;
    int loc[8];
    int s = 0;
    #pragma unroll
    for (int i = 0; i < 8; ++i) {
        int idx = base + i;
        int v = (idx < n) ? off[idx] : 0;
        s += v;
        loc[i] = s;
    }
    red[t] = s;
    __syncthreads();
    #pragma unroll
    for (int o = 1; o < 256; o <<= 1) {
        int u = (t >= o) ? red[t - o] : 0;
        __syncthreads();
        red[t] += u;
        __syncthreads();
    }
    int offset = part[blockIdx.x] + red[t] - s;
    #pragma unroll
    for (int i = 0; i < 8; ++i) {
        int idx = base + i;
        if (idx < n) off[idx] = loc[i] + offset;
    }
}

__global__ void gin_fill_kernel(const int* __restrict__ src, const int* __restrict__ dst,
                                int* __restrict__ off, int* __restrict__ csr, int E) {
    int e = blockIdx.x * 256 + threadIdx.x;
    if (e < E) {
        int d = dst[e];
        int p = atomicAdd(&off[d], 1);
        csr[p] = src[e];
    }
}

// ---------------- x -> fp16 ----------------
__global__ void gin_f2h_kernel(const float* __restrict__ x, __half* __restrict__ xh, int n4) {
    int i = blockIdx.x * 256 + threadIdx.x;
    if (i >= n4) return;
    float4 v = ((const float4*)x)[i];
    union { __half h[4]; uint2 u; } o;
    o.h[0] = __float2half(v.x); o.h[1] = __float2half(v.y);
    o.h[2] = __float2half(v.z); o.h[3] = __float2half(v.w);
    ((uint2*)xh)[i] = o.u;
}

// ---------------- weight pre-pack into MFMA B-fragment order (bf16 hi/lo) ----------------
__global__ void gin_pack_kernel(const float* __restrict__ W, int K, int N,
                                unsigned short* __restrict__ out) {
    int idx = blockIdx.x * 256 + threadIdx.x;
    int KC = K / 32, NT = N / 16;
    int total = 2 * KC * NT * 64 * 8;
    if (idx >= total) return;
    int j = idx & 7;
    int l = (idx >> 3) & 63;
    int v = idx >> 9;
    int nt = v % NT; v /= NT;
    int kc = v % KC;
    int spl = v / KC;
    int k = kc * 32 + (l >> 4) * 8 + j;
    int n = nt * 16 + (l & 15);
    float w = W[(size_t)k * N + n];
    unsigned short hi, lo;
    split_bf16(w, hi, lo);
    out[idx] = (spl == 0) ? hi : lo;
}

// ---------------- aggregation: z = (1+eps)*h + mean_neigh -> (zh, zl) bf16 split ----------------
// h is fp16. 8 nodes / 256-thread block; 32 lanes x 4 channels per node.
__global__ __launch_bounds__(256)
void gin_agg_kernel(const __half* __restrict__ h, const int* __restrict__ offend,
                    const int* __restrict__ csr, const float* __restrict__ eps, int layer,
                    unsigned short* __restrict__ zh, unsigned short* __restrict__ zl, int n) {
    int node = blockIdx.x * 8 + (threadIdx.x >> 5);
    if (node >= n) return;
    int lane = threadIdx.x & 31;
    int lo = node ? offend[node - 1] : 0;
    int hi = offend[node];

    float s0 = 0.f, s1 = 0.f, s2 = 0.f, s3 = 0.f;
    float t0 = 0.f, t1 = 0.f, t2 = 0.f, t3 = 0.f;
    int e = lo;
    for (; e + 1 < hi; e += 2) {
        int a = csr[e], b = csr[e + 1];
        uint2 ra = *(const uint2*)(h + (size_t)a * NCH + lane * 4);
        uint2 rb = *(const uint2*)(h + (size_t)b * NCH + lane * 4);
        float2 a0 = __half22float2(*(__half2*)&ra.x);
        float2 a1 = __half22float2(*(__half2*)&ra.y);
        float2 b0 = __half22float2(*(__half2*)&rb.x);
        float2 b1 = __half22float2(*(__half2*)&rb.y);
        s0 += a0.x; s1 += a0.y; s2 += a1.x; s3 += a1.y;
        t0 += b0.x; t1 += b0.y; t2 += b1.x; t3 += b1.y;
    }
    if (e < hi) {
        int a = csr[e];
        uint2 ra = *(const uint2*)(h + (size_t)a * NCH + lane * 4);
        float2 a0 = __half22float2(*(__half2*)&ra.x);
        float2 a1 = __half22float2(*(__half2*)&ra.y);
        s0 += a0.x; s1 += a0.y; s2 += a1.x; s3 += a1.y;
    }
    float invd = 1.0f / fmaxf((float)(hi - lo), 1.0f);
    uint2 rs = *(const uint2*)(h + (size_t)node * NCH + lane * 4);
    float2 x0 = __half22float2(*(__half2*)&rs.x);
    float2 x1 = __half22float2(*(__half2*)&rs.y);
    float e1 = 1.0f + eps[layer];
    float z0 = e1 * x0.x + (s0 + t0) * invd;
    float z1 = e1 * x0.y + (s1 + t1) * invd;
    float z2 = e1 * x1.x + (s2 + t2) * invd;
    float z3 = e1 * x1.y + (s3 + t3) * invd;

    ushort4 hv, lv;
    split_bf16(z0, hv.x, lv.x);
    split_bf16(z1, hv.y, lv.y);
    split_bf16(z2, hv.z, lv.z);
    split_bf16(z3, hv.w, lv.w);
    *(ushort4*)(zh + (size_t)node * NCH + lane * 4) = hv;
    *(ushort4*)(zl + (size_t)node * NCH + lane * 4) = lv;
}

// ---------------- fused 2-GEMM MLP on matrix cores (split-bf16, 3 MFMA terms) ----------------
// 256 threads = 4 waves, 64 rows/block, 16 rows/wave. Wave-private LDS T-slice
// (16 x (N1+4) f32) -> 4 waves share 33.8KB but occupancy cap is 16 waves/CU
// (VGPR<=128 via launch_bounds). One barrier for LDS write->read ordering safety.
template <int N1, int N2, typename OutT>
__global__ __launch_bounds__(256, 4)
void gin_mlp_mfma(const unsigned short* __restrict__ Zh, const unsigned short* __restrict__ Zl,
                  const unsigned short* __restrict__ PW1, const float* __restrict__ B1,
                  const unsigned short* __restrict__ PW2, const float* __restrict__ B2,
                  OutT* __restrict__ Out, int nrows) {
    constexpr int K1 = 128;
    constexpr int KC1 = K1 / 32, NT1 = N1 / 16, KC2 = N1 / 32, NT2 = N2 / 16;
    constexpr int TS = N1 + 4;  // f32 stride: 16B-aligned rows, <=2-way bank conflicts
    __shared__ __align__(16) float Tlds[4 * 16 * TS];

    const int tid = threadIdx.x;
    const int w = tid >> 6;
    const int l = tid & 63;
    const int lr = l & 15;   // A-row / B-col / C-col within 16x16 tile
    const int lg = l >> 4;   // k-group; C-row = lg*4+r
    const int m0 = blockIdx.x * 64 + w * 16;  // this wave's 16-row band
    float* tw = &Tlds[w * 16 * TS];

    // ---- GEMM1: T = leaky(Z @ W1 + b1) ----
    f32x4 acc[NT1];
    #pragma unroll
    for (int nt = 0; nt < NT1; ++nt) acc[nt] = {0.f, 0.f, 0.f, 0.f};

    #pragma unroll
    for (int kc = 0; kc < KC1; ++kc) {
        bf16x8 ah, al;
        int row = m0 + lr;
        if (row < nrows) {
            size_t zo = (size_t)row * K1 + kc * 32 + lg * 8;
            ah = *(const bf16x8*)(Zh + zo);
            al = *(const bf16x8*)(Zl + zo);
        } else {
            ah = (bf16x8){0,0,0,0,0,0,0,0};
            al = (bf16x8){0,0,0,0,0,0,0,0};
        }
        #pragma unroll
        for (int nt = 0; nt < NT1; ++nt) {
            const unsigned short* pb = PW1 + (((size_t)kc * NT1 + nt) * 64 + l) * 8;
            bf16x8 bh = *(const bf16x8*)pb;
            bf16x8 bl = *(const bf16x8*)(pb + (size_t)KC1 * NT1 * 512);
            acc[nt] = __builtin_amdgcn_mfma_f32_16x16x32_bf16(ah, bh, acc[nt], 0, 0, 0);
            acc[nt] = __builtin_amdgcn_mfma_f32_16x16x32_bf16(ah, bl, acc[nt], 0, 0, 0);
            acc[nt] = __builtin_amdgcn_mfma_f32_16x16x32_bf16(al, bh, acc[nt], 0, 0, 0);
        }
    }

    // epilogue 1: bias + leaky -> wave-private LDS (C/D: row=lg*4+r, col=nt*16+lr)
    #pragma unroll
    for (int nt = 0; nt < NT1; ++nt) {
        float bb = B1[nt * 16 + lr];
        #pragma unroll
        for (int r = 0; r < 4; ++r) {
            float v = acc[nt][r] + bb;
            v = v > 0.f ? v : 0.01f * v;
            tw[(lg * 4 + r) * TS + nt * 16 + lr] = v;
        }
    }
    __syncthreads();

    // ---- GEMM2: out = leaky(T @ W2 + b2) ----
    f32x4 acc2[NT2];
    #pragma unroll
    for (int nt = 0; nt < NT2; ++nt) acc2[nt] = {0.f, 0.f, 0.f, 0.f};

    #pragma unroll
    for (int kc = 0; kc < KC2; ++kc) {
        const float* tp = &tw[lr * TS + kc * 32 + lg * 8];
        f32x4 v0 = *(const f32x4*)tp;
        f32x4 v1 = *(const f32x4*)(tp + 4);
        union { bf16x8 v; unsigned short u[8]; } H, L;
        #pragma unroll
        for (int i = 0; i < 4; ++i) {
            split_bf16(v0[i], H.u[i], L.u[i]);
            split_bf16(v1[i], H.u[i + 4], L.u[i + 4]);
        }
        bf16x8 ah = H.v, al = L.v;
        #pragma unroll
        for (int nt = 0; nt < NT2; ++nt) {
            const unsigned short* pb = PW2 + (((size_t)kc * NT2 + nt) * 64 + l) * 8;
            bf16x8 bh = *(const bf16x8*)pb;
            bf16x8 bl = *(const bf16x8*)(pb + (size_t)KC2 * NT2 * 512);
            acc2[nt] = __builtin_amdgcn_mfma_f32_16x16x32_bf16(ah, bh, acc2[nt], 0, 0, 0);
            acc2[nt] = __builtin_amdgcn_mfma_f32_16x16x32_bf16(ah, bl, acc2[nt], 0, 0, 0);
            acc2[nt] = __builtin_amdgcn_mfma_f32_16x16x32_bf16(al, bh, acc2[nt], 0, 0, 0);
        }
    }

    // epilogue 2: bias + leaky -> global (fp16 for hidden layers, f32 for final)
    #pragma unroll
    for (int nt = 0; nt < NT2; ++nt) {
        float bb = B2[nt * 16 + lr];
        #pragma unroll
        for (int r = 0; r < 4; ++r) {
            int row = m0 + lg * 4 + r;
            if (row < nrows) {
                float v = acc2[nt][r] + bb;
                v = v > 0.f ? v : 0.01f * v;
                Out[(size_t)row * N2 + nt * 16 + lr] = (OutT)v;
            }
        }
    }
}

// ---------------- launch ----------------

extern "C" void kernel_launch(void* const* d_in, const int* in_sizes, int n_in,
                              void* d_out, int out_size, void* d_ws, size_t ws_size,
                              hipStream_t stream) {
    const float* x   = (const float*)d_in[0];
    const int*   src = (const int*)d_in[1];
    const int*   dst = (const int*)d_in[2];
    const float* eps = (const float*)d_in[3];
    const float* w1s = (const float*)d_in[4];
    const float* b1s = (const float*)d_in[5];
    const float* w2s = (const float*)d_in[6];
    const float* b2s = (const float*)d_in[7];
    const float* wf1 = (const float*)d_in[8];
    const float* bf1 = (const float*)d_in[9];
    const float* wf2 = (const float*)d_in[10];
    const float* bf2 = (const float*)d_in[11];

    const int N = in_sizes[0] / NCH;   // 100000
    const int E = in_sizes[1];         // 600000

    auto align256 = [](size_t v) { return (v + 255) & ~(size_t)255; };
    char* p = (char*)d_ws;
    int* off = (int*)p;              p += align256((size_t)(N + 1) * 4);
    int* part = (int*)p;             p += align256(1024 * 4);
    int* csr = (int*)p;              p += align256((size_t)E * 4);
    __half* xh = (__half*)p;         p += align256((size_t)N * NCH * 2);
    __half* hh = (__half*)p;         p += align256((size_t)N * NCH * 2);
    unsigned short* zh = (unsigned short*)p; p += (size_t)N * NCH * 2;
    unsigned short* zl = (unsigned short*)p; p += (size_t)N * NCH * 2;
    unsigned short* pw1 = (unsigned short*)p; p += 3 * 65536;
    unsigned short* pw2 = (unsigned short*)p; p += 3 * 65536;
    unsigned short* pwf1 = (unsigned short*)p; p += 32768;
    unsigned short* pwf2 = (unsigned short*)p;

    // CSR build
    const int nScan = N + 1;
    const int nTiles = (nScan + 2047) / 2048;
    hipMemsetAsync(off, 0, (size_t)nScan * 4, stream);
    gin_deg_kernel<<<(E + 255) / 256, 256, 0, stream>>>(dst, off, E);
    gin_scan1<<<nTiles, 256, 0, stream>>>(off, part, nScan);
    gin_scan2<<<1, 256, 0, stream>>>(part, nTiles);
    gin_scan3<<<nTiles, 256, 0, stream>>>(off, part, nScan);
    gin_fill_kernel<<<(E + 255) / 256, 256, 0, stream>>>(src, dst, off, csr, E);

    // x -> fp16 copy for gathering
    const int n4 = N * NCH / 4;
    gin_f2h_kernel<<<(n4 + 255) / 256, 256, 0, stream>>>(x, xh, n4);

    // pack weights
    for (int layer = 0; layer < 3; ++layer) {
        gin_pack_kernel<<<128, 256, 0, stream>>>(w1s + (size_t)layer * 128 * 128, 128, 128,
                                                 (unsigned short*)((char*)pw1 + (size_t)layer * 65536));
        gin_pack_kernel<<<128, 256, 0, stream>>>(w2s + (size_t)layer * 128 * 128, 128, 128,
                                                 (unsigned short*)((char*)pw2 + (size_t)layer * 65536));
    }
    gin_pack_kernel<<<64, 256, 0, stream>>>(wf1, 128, 64, pwf1);
    gin_pack_kernel<<<32, 256, 0, stream>>>(wf2, 64, 64, pwf2);

    const int aggGrid = (N + 7) / 8;
    const int mlpGrid = (N + 63) / 64;

    gin_agg_kernel<<<aggGrid, 256, 0, stream>>>(xh, off, csr, eps, 0, zh, zl, N);
    gin_mlp_mfma<128, 128, __half><<<mlpGrid, 256, 0, stream>>>(
        zh, zl, pw1, b1s, pw2, b2s, hh, N);
    for (int layer = 1; layer < 3; ++layer) {
        gin_agg_kernel<<<aggGrid, 256, 0, stream>>>(hh, off, csr, eps, layer, zh, zl, N);
        gin_mlp_mfma<128, 128, __half><<<mlpGrid, 256, 0, stream>>>(
            zh, zl,
            (unsigned short*)((char*)pw1 + (size_t)layer * 65536), b1s + (size_t)layer * 128,
            (unsigned short*)((char*)pw2 + (size_t)layer * 65536), b2s + (size_t)layer * 128,
            hh, N);
    }
    gin_agg_kernel<<<aggGrid, 256, 0, stream>>>(hh, off, csr, eps, 3, zh, zl, N);
    gin_mlp_mfma<64, 64, float><<<mlpGrid, 256, 0, stream>>>(
        zh, zl, pwf1, bf1, pwf2, bf2, (float*)d_out, N);
}